// Round 1
// baseline (4338.628 us; speedup 1.0000x reference)
//
#include <hip/hip_runtime.h>

// Problem constants
#define BN_TOK 2400     // B*N = 8*300
#define QDIM   256
#define NG     4
#define FLAT   32768    // G * (EOUT*POUT) = 4*8192
#define GSZ    8192
#define CT     300      // tokens per chunk
#define NCH    8        // BN_TOK / CT
#define JSPLIT 64
#define JRANGE (FLAT / JSPLIT)   // 512
#define LN_EPS 1e-5f

// ---------------------------------------------------------------- build W^T
// Wt[j][i] = base_w[i][j] + sum_r lora_B[i][r] * lora_A[r][j]
__global__ __launch_bounds__(256) void build_wt_k(
    const float* __restrict__ base_w, const float* __restrict__ lora_A,
    const float* __restrict__ lora_B, float* __restrict__ Wt) {
  int tid = threadIdx.x;
  int jb = blockIdx.x * 64;
  int ib = blockIdx.y * 64;
  __shared__ float lA[64][65];  // [r][jloc]
  __shared__ float lB[64][65];  // [iloc][r]
#pragma unroll
  for (int it = 0; it < 16; ++it) {
    int e = tid + it * 256;
    int r = e >> 6, jl = e & 63;
    lA[r][jl] = lora_A[(size_t)r * FLAT + jb + jl];
  }
#pragma unroll
  for (int it = 0; it < 16; ++it) {
    int e = tid + it * 256;
    int il = e >> 6, r = e & 63;
    lB[il][r] = lora_B[(size_t)(ib + il) * 64 + r];
  }
  __syncthreads();
  int iloc = tid & 63;
  int jq = tid >> 6;
#pragma unroll
  for (int jm = 0; jm < 16; ++jm) {
    int jl = jq * 16 + jm;
    float acc = 0.f;
#pragma unroll
    for (int r = 0; r < 64; ++r) acc += lB[iloc][r] * lA[r][jl];
    Wt[(size_t)(jb + jl) * QDIM + ib + iloc] =
        base_w[(size_t)(ib + iloc) * FLAT + jb + jl] + acc;
  }
}

// ---------------------------------------------------------------- priv GEMV
// priv[t][u] = dot(q[t], ppg_w[u]) + ppg_b[u],  u < 512
__global__ __launch_bounds__(256) void priv_k(
    const float* __restrict__ query, const float* __restrict__ ppg_w,
    const float* __restrict__ ppg_b, float* __restrict__ priv) {
  int tid = threadIdx.x;
  int t = blockIdx.x;
  __shared__ float qs[QDIM];
  qs[tid] = query[(size_t)t * QDIM + tid];
  __syncthreads();
  int w = tid >> 6, lane = tid & 63;
  float4 qv = ((const float4*)qs)[lane];
  for (int u = w; u < 512; u += 4) {
    float4 pw = ((const float4*)(ppg_w + (size_t)u * QDIM))[lane];
    float s = pw.x * qv.x + pw.y * qv.y + pw.z * qv.z + pw.w * qv.w;
#pragma unroll
    for (int off = 32; off > 0; off >>= 1) s += __shfl_down(s, off);
    if (lane == 0) priv[(size_t)t * 512 + u] = s + ppg_b[u];
  }
}

// ---------------------------------------------------------------- GEMM1
// common[tt][col] = dot(q[t0+tt], cpg_w[col]) + cpg_b[col]  (tt local in chunk)
__global__ __launch_bounds__(256) void gemm1_k(
    const float* __restrict__ query, const float* __restrict__ cpg_w,
    const float* __restrict__ cpg_b, float* __restrict__ common, int t0) {
  int tid = threadIdx.x;
  int tb = blockIdx.x * 64;
  int cb = blockIdx.y * 64;
  __shared__ float As[64][65];  // [tt][k]
  __shared__ float Bs[64][65];  // [c][k]
  float acc[4][4] = {};
  int ty = tid >> 4, tx = tid & 15;
  for (int kb = 0; kb < QDIM; kb += 64) {
#pragma unroll
    for (int it = 0; it < 16; ++it) {
      int e = tid + it * 256;
      int tt = e >> 6, k = e & 63;
      int tg = tb + tt;
      As[tt][k] = (tg < CT) ? query[(size_t)(t0 + tg) * QDIM + kb + k] : 0.f;
    }
#pragma unroll
    for (int it = 0; it < 16; ++it) {
      int e = tid + it * 256;
      int c = e >> 6, k = e & 63;
      Bs[c][k] = cpg_w[(size_t)(cb + c) * QDIM + kb + k];
    }
    __syncthreads();
#pragma unroll 4
    for (int k = 0; k < 64; ++k) {
      float a[4], b[4];
#pragma unroll
      for (int j = 0; j < 4; ++j) a[j] = As[ty * 4 + j][k];
#pragma unroll
      for (int i = 0; i < 4; ++i) b[i] = Bs[tx * 4 + i][k];
#pragma unroll
      for (int j = 0; j < 4; ++j)
#pragma unroll
        for (int i = 0; i < 4; ++i) acc[j][i] += a[j] * b[i];
    }
    __syncthreads();
  }
#pragma unroll
  for (int j = 0; j < 4; ++j) {
    int tt = tb + ty * 4 + j;
    if (tt < CT) {
#pragma unroll
      for (int i = 0; i < 4; ++i) {
        int c = cb + tx * 4 + i;
        common[(size_t)tt * FLAT + c] = acc[j][i] + cpg_b[c];
      }
    }
  }
}

// ---------------------------------------------------------------- chain
__device__ __forceinline__ void block_red2(float& s, float& sq, float* redS,
                                           float* redQ, int tid) {
#pragma unroll
  for (int off = 32; off > 0; off >>= 1) {
    s += __shfl_down(s, off);
    sq += __shfl_down(sq, off);
  }
  int w = tid >> 6;
  if ((tid & 63) == 0) { redS[w] = s; redQ[w] = sq; }
  __syncthreads();
  s = redS[0] + redS[1] + redS[2] + redS[3];
  sq = redQ[0] + redQ[1] + redQ[2] + redQ[3];
}

__global__ __launch_bounds__(256) void chain_k(
    const float* __restrict__ x, const float* __restrict__ priv,
    const float* __restrict__ ml, const float* __restrict__ mr,
    const float* __restrict__ sl, const float* __restrict__ sr,
    float* __restrict__ common, int t0) {
  int tid = threadIdx.x;
  int tl = blockIdx.x;
  int g = blockIdx.y;
  int t = t0 + tl;
  __shared__ float Ms[64][64];
  __shared__ float Ss[128][32];
  __shared__ float xs[32][64];
  __shared__ float o1[32][64];
  __shared__ float mzs[64], szs[64];
  __shared__ float Am[64][8];
  __shared__ float Aso[128][8];
  __shared__ float redS[4], redQ[4];

  if (tid < 64) mzs[tid] = priv[(size_t)t * 512 + g * 64 + tid];
  else if (tid < 128) szs[tid - 64] = priv[(size_t)t * 512 + 256 + g * 64 + (tid - 64)];
  __syncthreads();

  // Am[c][l] = sum_k ml[g,c,k] * mz[k,l]
  for (int e = tid; e < 512; e += 256) {
    int c = e >> 3, l = e & 7;
    float s = 0.f;
#pragma unroll
    for (int k = 0; k < 8; ++k) s += ml[g * 512 + c * 8 + k] * mzs[k * 8 + l];
    Am[c][l] = s;
  }
  // Aso[o][l] = sum_k sl[g,o,k] * sz[k,l]
  for (int e = tid; e < 1024; e += 256) {
    int o = e >> 3, l = e & 7;
    float s = 0.f;
#pragma unroll
    for (int k = 0; k < 8; ++k) s += sl[g * 1024 + o * 8 + k] * szs[k * 8 + l];
    Aso[o][l] = s;
  }
  __syncthreads();

  const float* cm = common + (size_t)tl * FLAT + g * GSZ;
  // M = Mc + Am @ mr
  for (int e = tid; e < 4096; e += 256) {
    int c = e >> 6, d = e & 63;
    float mp = 0.f;
#pragma unroll
    for (int l = 0; l < 8; ++l) mp += Am[c][l] * mr[g * 512 + l * 64 + d];
    Ms[c][d] = cm[e] + mp;
  }
  // S = Sc + Aso @ sr
  for (int e = tid; e < 4096; e += 256) {
    int o = e >> 5, p = e & 31;
    float sp = 0.f;
#pragma unroll
    for (int l = 0; l < 8; ++l) sp += Aso[o][l] * sr[g * 256 + l * 32 + p];
    Ss[o][p] = cm[4096 + e] + sp;
  }
  for (int e = tid; e < 2048; e += 256)
    xs[e >> 6][e & 63] = x[(size_t)t * 8192 + g * 2048 + e];
  __syncthreads();

  // out1[p][d] = sum_c xs[p][c] * Ms[c][d]
  int d = tid & 63, q4 = tid >> 6;
  float a1[8] = {};
  for (int c = 0; c < 64; ++c) {
    float m = Ms[c][d];
#pragma unroll
    for (int j = 0; j < 8; ++j) a1[j] += xs[q4 * 8 + j][c] * m;
  }
  // LN1 over 2048 + ReLU
  float s = 0.f, sq = 0.f;
#pragma unroll
  for (int j = 0; j < 8; ++j) { s += a1[j]; sq += a1[j] * a1[j]; }
  block_red2(s, sq, redS, redQ, tid);
  float mean = s * (1.f / 2048.f);
  float var = sq * (1.f / 2048.f) - mean * mean;
  float rs = rsqrtf(var + LN_EPS);
#pragma unroll
  for (int j = 0; j < 8; ++j) {
    float v = (a1[j] - mean) * rs;
    o1[q4 * 8 + j][d] = v > 0.f ? v : 0.f;
  }
  __syncthreads();

  // out2[o][d] = sum_p Ss[o][p] * o1[p][d]
  float a2[32] = {};
  for (int p = 0; p < 32; ++p) {
    float v = o1[p][d];
#pragma unroll
    for (int j = 0; j < 32; ++j) a2[j] += Ss[q4 * 32 + j][p] * v;
  }
  // LN2 over 8192 + ReLU, write back in place
  s = 0.f; sq = 0.f;
#pragma unroll
  for (int j = 0; j < 32; ++j) { s += a2[j]; sq += a2[j] * a2[j]; }
  block_red2(s, sq, redS, redQ, tid);
  float mean2 = s * (1.f / 8192.f);
  float var2 = sq * (1.f / 8192.f) - mean2 * mean2;
  float rs2 = rsqrtf(var2 + LN_EPS);
  float* co = common + (size_t)tl * FLAT + g * GSZ;
#pragma unroll
  for (int j = 0; j < 32; ++j) {
    float v = (a2[j] - mean2) * rs2;
    co[(q4 * 32 + j) * 64 + d] = v > 0.f ? v : 0.f;
  }
}

// ---------------------------------------------------------------- GEMM2 (split-K)
// partial[ks][tt][i] = sum_{j in ks-range} out2[tt][j] * Wt[j][i]
__global__ __launch_bounds__(256) void gemm2_k(
    const float* __restrict__ common, const float* __restrict__ Wt,
    float* __restrict__ partial) {
  int tid = threadIdx.x;
  int tb = blockIdx.x * 64;
  int jb = blockIdx.y * JRANGE;
  __shared__ float o2[64][36];
  float acc[64];
#pragma unroll
  for (int tt = 0; tt < 64; ++tt) acc[tt] = 0.f;
  for (int jc = 0; jc < JRANGE; jc += 32) {
    int jj = jb + jc;
#pragma unroll
    for (int it = 0; it < 8; ++it) {
      int e = tid + it * 256;
      int tt = e >> 5, j = e & 31;
      int tg = tb + tt;
      o2[tt][j] = (tg < CT) ? common[(size_t)tg * FLAT + jj + j] : 0.f;
    }
    __syncthreads();
    for (int j4 = 0; j4 < 32; j4 += 4) {
      float w0 = Wt[(size_t)(jj + j4 + 0) * QDIM + tid];
      float w1 = Wt[(size_t)(jj + j4 + 1) * QDIM + tid];
      float w2 = Wt[(size_t)(jj + j4 + 2) * QDIM + tid];
      float w3 = Wt[(size_t)(jj + j4 + 3) * QDIM + tid];
#pragma unroll
      for (int tt = 0; tt < 64; ++tt) {
        float4 v = *(const float4*)&o2[tt][j4];
        acc[tt] += v.x * w0 + v.y * w1 + v.z * w2 + v.w * w3;
      }
    }
    __syncthreads();
  }
  int ks = blockIdx.y;
  for (int tt = 0; tt < 64; ++tt) {
    int tg = tb + tt;
    if (tg < CT) partial[((size_t)ks * CT + tg) * QDIM + tid] = acc[tt];
  }
}

// ---------------------------------------------------------------- finish
__global__ __launch_bounds__(256) void finish_k(
    const float* __restrict__ partial, const float* __restrict__ query,
    const float* __restrict__ out_bias, const float* __restrict__ gamma,
    const float* __restrict__ beta, float* __restrict__ out, int t0) {
  int tid = threadIdx.x;
  int tl = blockIdx.x;
  int t = t0 + tl;
  __shared__ float redS[4], redQ[4];
  float s = 0.f;
  for (int ks = 0; ks < JSPLIT; ++ks)
    s += partial[((size_t)ks * CT + tl) * QDIM + tid];
  float v = s + out_bias[tid] + query[(size_t)t * QDIM + tid];
  float sum = v, sqv = v * v;
  block_red2(sum, sqv, redS, redQ, tid);
  float mean = sum * (1.f / 256.f);
  float var = sqv * (1.f / 256.f) - mean * mean;
  out[(size_t)t * QDIM + tid] =
      (v - mean) * rsqrtf(var + LN_EPS) * gamma[tid] + beta[tid];
}

// ---------------------------------------------------------------- launch
extern "C" void kernel_launch(void* const* d_in, const int* in_sizes, int n_in,
                              void* d_out, int out_size, void* d_ws, size_t ws_size,
                              hipStream_t stream) {
  const float* x       = (const float*)d_in[1];
  const float* query   = (const float*)d_in[2];
  const float* cpg_w   = (const float*)d_in[3];
  const float* cpg_b   = (const float*)d_in[4];
  const float* ppg_w   = (const float*)d_in[5];
  const float* ppg_b   = (const float*)d_in[6];
  const float* ml      = (const float*)d_in[7];
  const float* mr      = (const float*)d_in[8];
  const float* sl      = (const float*)d_in[9];
  const float* sr      = (const float*)d_in[10];
  const float* base_w  = (const float*)d_in[11];
  const float* lora_A  = (const float*)d_in[12];
  const float* lora_B  = (const float*)d_in[13];
  const float* out_bias= (const float*)d_in[14];
  const float* gamma   = (const float*)d_in[15];
  const float* beta    = (const float*)d_in[16];
  float* out = (float*)d_out;

  float* wsf     = (float*)d_ws;
  float* Wt      = wsf;                  //  8,388,608 floats
  float* privb   = wsf + 8388608;        //  1,228,800 floats
  float* commonb = wsf + 9617408;        //  9,830,400 floats (CT*FLAT)
  float* partialb= wsf + 19447808;       //  4,915,200 floats (JSPLIT*CT*QDIM)
  // total = 24,363,008 floats = 97.5 MB

  build_wt_k<<<dim3(FLAT / 64, QDIM / 64), 256, 0, stream>>>(base_w, lora_A, lora_B, Wt);
  priv_k<<<dim3(BN_TOK), 256, 0, stream>>>(query, ppg_w, ppg_b, privb);

  for (int ch = 0; ch < NCH; ++ch) {
    int t0 = ch * CT;
    gemm1_k<<<dim3((CT + 63) / 64, FLAT / 64), 256, 0, stream>>>(query, cpg_w, cpg_b, commonb, t0);
    chain_k<<<dim3(CT, NG), 256, 0, stream>>>(x, privb, ml, mr, sl, sr, commonb, t0);
    gemm2_k<<<dim3((CT + 63) / 64, JSPLIT), 256, 0, stream>>>(commonb, Wt, partialb);
    finish_k<<<dim3(CT), 256, 0, stream>>>(partialb, query, out_bias, gamma, beta, out, t0);
  }
}

// Round 2
// 969.694 us; speedup vs baseline: 4.4742x; 4.4742x over previous
//
#include <hip/hip_runtime.h>
#include <hip/hip_bf16.h>

// Problem constants
#define BN_TOK 2400     // B*N = 8*300
#define QDIM   256
#define NG     4
#define FLAT   32768    // G * (EOUT*POUT) = 4*8192
#define GSZ    8192
#define CT     300      // tokens per chunk
#define NCH    8        // BN_TOK / CT
#define KSP    32       // split-K ways for gemm2
#define KRANGE (FLAT / KSP)   // 1024
#define LN_EPS 1e-5f

typedef __attribute__((ext_vector_type(8))) short bf16x8;
typedef __attribute__((ext_vector_type(4))) float f32x4;
typedef __hip_bfloat16 bf16;

// ---------------------------------------------------------------- fp32 -> bf16 cast
__global__ __launch_bounds__(256) void cast_k(const float* __restrict__ in,
                                              bf16* __restrict__ out, int n4) {
  int i = blockIdx.x * 256 + threadIdx.x;
  if (i < n4) {
    float4 v = ((const float4*)in)[i];
    bf16 tmp[4] = {__float2bfloat16(v.x), __float2bfloat16(v.y),
                   __float2bfloat16(v.z), __float2bfloat16(v.w)};
    ((ushort4*)out)[i] = *(const ushort4*)tmp;
  }
}

// ---------------------------------------------------------------- W = base_w + lora_B@lora_A (bf16, row-major [QDIM][FLAT])
__global__ __launch_bounds__(256) void build_wb_k(
    const float* __restrict__ base_w, const float* __restrict__ lora_A,
    const float* __restrict__ lora_B, bf16* __restrict__ Wb) {
  int jb = blockIdx.x * 256;
  int i0 = blockIdx.y * 16;
  int tid = threadIdx.x;
  __shared__ float lB[16][64];
  for (int e = tid; e < 16 * 64; e += 256)
    lB[e >> 6][e & 63] = lora_B[(size_t)(i0 + (e >> 6)) * 64 + (e & 63)];
  __syncthreads();
  int j = jb + tid;
  float acc[16] = {};
  for (int r = 0; r < 64; ++r) {
    float la = lora_A[(size_t)r * FLAT + j];
#pragma unroll
    for (int i = 0; i < 16; ++i) acc[i] += lB[i][r] * la;
  }
#pragma unroll
  for (int i = 0; i < 16; ++i)
    Wb[(size_t)(i0 + i) * FLAT + j] =
        __float2bfloat16(base_w[(size_t)(i0 + i) * FLAT + j] + acc[i]);
}

// ---------------------------------------------------------------- priv GEMV
__global__ __launch_bounds__(256) void priv_k(
    const float* __restrict__ query, const float* __restrict__ ppg_w,
    const float* __restrict__ ppg_b, float* __restrict__ priv) {
  int tid = threadIdx.x;
  int t = blockIdx.x;
  __shared__ float qs[QDIM];
  qs[tid] = query[(size_t)t * QDIM + tid];
  __syncthreads();
  int w = tid >> 6, lane = tid & 63;
  float4 qv = ((const float4*)qs)[lane];
  for (int u = w; u < 512; u += 4) {
    float4 pw = ((const float4*)(ppg_w + (size_t)u * QDIM))[lane];
    float s = pw.x * qv.x + pw.y * qv.y + pw.z * qv.z + pw.w * qv.w;
#pragma unroll
    for (int off = 32; off > 0; off >>= 1) s += __shfl_down(s, off);
    if (lane == 0) priv[(size_t)t * 512 + u] = s + ppg_b[u];
  }
}

// ---------------------------------------------------------------- GEMM1 (MFMA): common = qb @ cpg_wb^T + cpg_b
// A = qb [2400][256] bf16 (K contiguous), B = cpg_wb [32768][256] bf16 (B^T layout)
__global__ __launch_bounds__(256) void gemm1_mfma(
    const bf16* __restrict__ qb, const bf16* __restrict__ wb,
    const float* __restrict__ cpg_b, float* __restrict__ common, int t0) {
  __shared__ ushort As[128 * 32];  // 8 KB
  __shared__ ushort Bs[128 * 32];  // 8 KB
  int tid = threadIdx.x;
  int w = tid >> 6, lane = tid & 63;
  int m0 = blockIdx.x * 128;  // chunk-local token tile base
  int n0 = blockIdx.y * 128;
  int wm = (w & 1) * 64, wn = (w >> 1) * 64;
  f32x4 acc[4][4] = {};
  for (int kb = 0; kb < QDIM; kb += 32) {
#pragma unroll
    for (int i = 0; i < 2; ++i) {
      int chunk = (w * 2 + i) * 64 + lane;  // 0..511, 16B each
      int row = chunk >> 2;
      int kc = (chunk & 3) * 8;
      int grow = m0 + row;
      if (grow >= CT) grow = CT - 1;  // clamp OOB token rows
      const bf16* src = qb + (size_t)(t0 + grow) * QDIM + kb + kc;
      __builtin_amdgcn_global_load_lds(
          (const __attribute__((address_space(1))) void*)src,
          (__attribute__((address_space(3))) void*)(As + (size_t)chunk * 8), 16, 0, 0);
    }
#pragma unroll
    for (int i = 0; i < 2; ++i) {
      int chunk = (w * 2 + i) * 64 + lane;
      int row = chunk >> 2;
      int kc = (chunk & 3) * 8;
      const bf16* src = wb + (size_t)(n0 + row) * QDIM + kb + kc;
      __builtin_amdgcn_global_load_lds(
          (const __attribute__((address_space(1))) void*)src,
          (__attribute__((address_space(3))) void*)(Bs + (size_t)chunk * 8), 16, 0, 0);
    }
    __syncthreads();
    bf16x8 af[4], bfr[4];
#pragma unroll
    for (int i = 0; i < 4; ++i) {
      int r = wm + i * 16 + (lane & 15);
      af[i] = *(const bf16x8*)&As[r * 32 + (lane >> 4) * 8];
      int c = wn + i * 16 + (lane & 15);
      bfr[i] = *(const bf16x8*)&Bs[c * 32 + (lane >> 4) * 8];
    }
#pragma unroll
    for (int i = 0; i < 4; ++i)
#pragma unroll
      for (int j = 0; j < 4; ++j)
        acc[i][j] = __builtin_amdgcn_mfma_f32_16x16x32_bf16(af[i], bfr[j], acc[i][j], 0, 0, 0);
    __syncthreads();
  }
#pragma unroll
  for (int i = 0; i < 4; ++i) {
    int rb = m0 + wm + i * 16 + (lane >> 4) * 4;
#pragma unroll
    for (int j = 0; j < 4; ++j) {
      int col = n0 + wn + j * 16 + (lane & 15);
      float bias = cpg_b[col];
#pragma unroll
      for (int r = 0; r < 4; ++r)
        if (rb + r < CT) common[(size_t)(rb + r) * FLAT + col] = acc[i][j][r] + bias;
    }
  }
}

// ---------------------------------------------------------------- chain (fp32 VALU, unchanged math; writes bf16 out2)
__device__ __forceinline__ void block_red2(float& s, float& sq, float* redS,
                                           float* redQ, int tid) {
#pragma unroll
  for (int off = 32; off > 0; off >>= 1) {
    s += __shfl_down(s, off);
    sq += __shfl_down(sq, off);
  }
  int w = tid >> 6;
  if ((tid & 63) == 0) { redS[w] = s; redQ[w] = sq; }
  __syncthreads();
  s = redS[0] + redS[1] + redS[2] + redS[3];
  sq = redQ[0] + redQ[1] + redQ[2] + redQ[3];
}

__global__ __launch_bounds__(256) void chain_k(
    const float* __restrict__ x, const float* __restrict__ priv,
    const float* __restrict__ ml, const float* __restrict__ mr,
    const float* __restrict__ sl, const float* __restrict__ sr,
    const float* __restrict__ common, bf16* __restrict__ o2b, int t0) {
  int tid = threadIdx.x;
  int tl = blockIdx.x;
  int g = blockIdx.y;
  int t = t0 + tl;
  __shared__ float Ms[64][64];
  __shared__ float Ss[128][32];
  __shared__ float xs[32][64];
  __shared__ float o1[32][64];
  __shared__ float mzs[64], szs[64];
  __shared__ float Am[64][8];
  __shared__ float Aso[128][8];
  __shared__ float redS[4], redQ[4];

  if (tid < 64) mzs[tid] = priv[(size_t)t * 512 + g * 64 + tid];
  else if (tid < 128) szs[tid - 64] = priv[(size_t)t * 512 + 256 + g * 64 + (tid - 64)];
  __syncthreads();

  for (int e = tid; e < 512; e += 256) {
    int c = e >> 3, l = e & 7;
    float s = 0.f;
#pragma unroll
    for (int k = 0; k < 8; ++k) s += ml[g * 512 + c * 8 + k] * mzs[k * 8 + l];
    Am[c][l] = s;
  }
  for (int e = tid; e < 1024; e += 256) {
    int o = e >> 3, l = e & 7;
    float s = 0.f;
#pragma unroll
    for (int k = 0; k < 8; ++k) s += sl[g * 1024 + o * 8 + k] * szs[k * 8 + l];
    Aso[o][l] = s;
  }
  __syncthreads();

  const float* cm = common + (size_t)tl * FLAT + g * GSZ;
  for (int e = tid; e < 4096; e += 256) {
    int c = e >> 6, d = e & 63;
    float mp = 0.f;
#pragma unroll
    for (int l = 0; l < 8; ++l) mp += Am[c][l] * mr[g * 512 + l * 64 + d];
    Ms[c][d] = cm[e] + mp;
  }
  for (int e = tid; e < 4096; e += 256) {
    int o = e >> 5, p = e & 31;
    float sp = 0.f;
#pragma unroll
    for (int l = 0; l < 8; ++l) sp += Aso[o][l] * sr[g * 256 + l * 32 + p];
    Ss[o][p] = cm[4096 + e] + sp;
  }
  for (int e = tid; e < 2048; e += 256)
    xs[e >> 6][e & 63] = x[(size_t)t * 8192 + g * 2048 + e];
  __syncthreads();

  int d = tid & 63, q4 = tid >> 6;
  float a1[8] = {};
  for (int c = 0; c < 64; ++c) {
    float m = Ms[c][d];
#pragma unroll
    for (int j = 0; j < 8; ++j) a1[j] += xs[q4 * 8 + j][c] * m;
  }
  float s = 0.f, sq = 0.f;
#pragma unroll
  for (int j = 0; j < 8; ++j) { s += a1[j]; sq += a1[j] * a1[j]; }
  block_red2(s, sq, redS, redQ, tid);
  float mean = s * (1.f / 2048.f);
  float var = sq * (1.f / 2048.f) - mean * mean;
  float rs = rsqrtf(var + LN_EPS);
#pragma unroll
  for (int j = 0; j < 8; ++j) {
    float v = (a1[j] - mean) * rs;
    o1[q4 * 8 + j][d] = v > 0.f ? v : 0.f;
  }
  __syncthreads();

  float a2[32] = {};
  for (int p = 0; p < 32; ++p) {
    float v = o1[p][d];
#pragma unroll
    for (int j = 0; j < 32; ++j) a2[j] += Ss[q4 * 32 + j][p] * v;
  }
  s = 0.f; sq = 0.f;
#pragma unroll
  for (int j = 0; j < 32; ++j) { s += a2[j]; sq += a2[j] * a2[j]; }
  block_red2(s, sq, redS, redQ, tid);
  float mean2 = s * (1.f / 8192.f);
  float var2 = sq * (1.f / 8192.f) - mean2 * mean2;
  float rs2 = rsqrtf(var2 + LN_EPS);
  bf16* ob = o2b + (size_t)tl * FLAT + g * GSZ;
#pragma unroll
  for (int j = 0; j < 32; ++j) {
    float v = (a2[j] - mean2) * rs2;
    ob[(q4 * 32 + j) * 64 + d] = __float2bfloat16(v > 0.f ? v : 0.f);
  }
}

// ---------------------------------------------------------------- GEMM2 (MFMA split-K): partial[ks] = o2b @ Wb^T (K-slice)
// A = o2b [384][32768] bf16, B = Wb [256][32768] bf16 (W row-major = B^T layout)
__global__ __launch_bounds__(256) void gemm2_mfma(
    const bf16* __restrict__ o2b, const bf16* __restrict__ Wb,
    float* __restrict__ partial) {
  __shared__ ushort As[128 * 32];
  __shared__ ushort Bs[128 * 32];
  int tid = threadIdx.x;
  int w = tid >> 6, lane = tid & 63;
  int m0 = blockIdx.x * 128;
  int n0 = blockIdx.y * 128;
  int kz = blockIdx.z;
  int wm = (w & 1) * 64, wn = (w >> 1) * 64;
  f32x4 acc[4][4] = {};
  for (int kb = kz * KRANGE; kb < (kz + 1) * KRANGE; kb += 32) {
#pragma unroll
    for (int i = 0; i < 2; ++i) {
      int chunk = (w * 2 + i) * 64 + lane;
      int row = chunk >> 2;
      int kc = (chunk & 3) * 8;
      const bf16* src = o2b + (size_t)(m0 + row) * FLAT + kb + kc;
      __builtin_amdgcn_global_load_lds(
          (const __attribute__((address_space(1))) void*)src,
          (__attribute__((address_space(3))) void*)(As + (size_t)chunk * 8), 16, 0, 0);
    }
#pragma unroll
    for (int i = 0; i < 2; ++i) {
      int chunk = (w * 2 + i) * 64 + lane;
      int row = chunk >> 2;
      int kc = (chunk & 3) * 8;
      const bf16* src = Wb + (size_t)(n0 + row) * FLAT + kb + kc;
      __builtin_amdgcn_global_load_lds(
          (const __attribute__((address_space(1))) void*)src,
          (__attribute__((address_space(3))) void*)(Bs + (size_t)chunk * 8), 16, 0, 0);
    }
    __syncthreads();
    bf16x8 af[4], bfr[4];
#pragma unroll
    for (int i = 0; i < 4; ++i) {
      int r = wm + i * 16 + (lane & 15);
      af[i] = *(const bf16x8*)&As[r * 32 + (lane >> 4) * 8];
      int c = wn + i * 16 + (lane & 15);
      bfr[i] = *(const bf16x8*)&Bs[c * 32 + (lane >> 4) * 8];
    }
#pragma unroll
    for (int i = 0; i < 4; ++i)
#pragma unroll
      for (int j = 0; j < 4; ++j)
        acc[i][j] = __builtin_amdgcn_mfma_f32_16x16x32_bf16(af[i], bfr[j], acc[i][j], 0, 0, 0);
    __syncthreads();
  }
#pragma unroll
  for (int i = 0; i < 4; ++i) {
    int rb = m0 + wm + i * 16 + (lane >> 4) * 4;
#pragma unroll
    for (int j = 0; j < 4; ++j) {
      int col = n0 + wn + j * 16 + (lane & 15);
#pragma unroll
      for (int r = 0; r < 4; ++r)
        if (rb + r < CT)
          partial[((size_t)kz * CT + rb + r) * QDIM + col] = acc[i][j][r];
    }
  }
}

// ---------------------------------------------------------------- finish: reduce split-K + bias + residual + LN
__global__ __launch_bounds__(256) void finish_k(
    const float* __restrict__ partial, const float* __restrict__ query,
    const float* __restrict__ out_bias, const float* __restrict__ gamma,
    const float* __restrict__ beta, float* __restrict__ out, int t0) {
  int tid = threadIdx.x;
  int tl = blockIdx.x;
  int t = t0 + tl;
  __shared__ float redS[4], redQ[4];
  float s = 0.f;
  for (int ks = 0; ks < KSP; ++ks)
    s += partial[((size_t)ks * CT + tl) * QDIM + tid];
  float v = s + out_bias[tid] + query[(size_t)t * QDIM + tid];
  float sum = v, sqv = v * v;
  block_red2(sum, sqv, redS, redQ, tid);
  float mean = sum * (1.f / 256.f);
  float var = sqv * (1.f / 256.f) - mean * mean;
  out[(size_t)t * QDIM + tid] =
      (v - mean) * rsqrtf(var + LN_EPS) * gamma[tid] + beta[tid];
}

// ---------------------------------------------------------------- launch
extern "C" void kernel_launch(void* const* d_in, const int* in_sizes, int n_in,
                              void* d_out, int out_size, void* d_ws, size_t ws_size,
                              hipStream_t stream) {
  const float* x       = (const float*)d_in[1];
  const float* query   = (const float*)d_in[2];
  const float* cpg_w   = (const float*)d_in[3];
  const float* cpg_b   = (const float*)d_in[4];
  const float* ppg_w   = (const float*)d_in[5];
  const float* ppg_b   = (const float*)d_in[6];
  const float* ml      = (const float*)d_in[7];
  const float* mr      = (const float*)d_in[8];
  const float* sl      = (const float*)d_in[9];
  const float* sr      = (const float*)d_in[10];
  const float* base_w  = (const float*)d_in[11];
  const float* lora_A  = (const float*)d_in[12];
  const float* lora_B  = (const float*)d_in[13];
  const float* out_bias= (const float*)d_in[14];
  const float* gamma   = (const float*)d_in[15];
  const float* beta    = (const float*)d_in[16];
  float* out = (float*)d_out;

  float* wsf = (float*)d_ws;
  // ws layout (float offsets):
  bf16*  Wb      = (bf16*)(wsf + 0);          // 256x32768 bf16   = 4,194,304 f
  bf16*  cpg_wb  = (bf16*)(wsf + 4194304);    // 32768x256 bf16   = 4,194,304 f
  bf16*  qb      = (bf16*)(wsf + 8388608);    // 2400x256 bf16    =   307,200 f
  float* privb   = wsf + 8695808;             // 2400x512 f32     = 1,228,800 f
  bf16*  o2b     = (bf16*)(wsf + 9924608);    // 384x32768 bf16   = 6,291,456 f
  float* commonb = wsf + 16216064;            // 300x32768 f32    = 9,830,400 f
  float* partialb= commonb;                   // alias: 32x300x256 f32 (2.45M f) reused after chain
  // total = 26,046,464 floats = 104.2 MB

  // one-time prep (re-run every call for determinism; ~40 us total)
  cast_k<<<dim3((FLAT * QDIM / 4 + 255) / 256), 256, 0, stream>>>(cpg_w, cpg_wb, FLAT * QDIM / 4);
  cast_k<<<dim3((BN_TOK * QDIM / 4 + 255) / 256), 256, 0, stream>>>(query, qb, BN_TOK * QDIM / 4);
  build_wb_k<<<dim3(FLAT / 256, QDIM / 16), 256, 0, stream>>>(base_w, lora_A, lora_B, Wb);
  priv_k<<<dim3(BN_TOK), 256, 0, stream>>>(query, ppg_w, ppg_b, privb);

  for (int ch = 0; ch < NCH; ++ch) {
    int t0 = ch * CT;
    gemm1_mfma<<<dim3(3, FLAT / 128), 256, 0, stream>>>(qb, cpg_wb, cpg_b, commonb, t0);
    chain_k<<<dim3(CT, NG), 256, 0, stream>>>(x, privb, ml, mr, sl, sr, commonb, o2b, t0);
    gemm2_mfma<<<dim3(3, QDIM / 128, KSP), 256, 0, stream>>>(o2b, Wb, partialb);
    finish_k<<<dim3(CT), 256, 0, stream>>>(partialb, query, out_bias, gamma, beta, out, t0);
  }
}

// Round 3
// 696.103 us; speedup vs baseline: 6.2327x; 1.3930x over previous
//
#include <hip/hip_runtime.h>
#include <hip/hip_bf16.h>

// Problem constants
#define BN_TOK 2400     // B*N = 8*300
#define QDIM   256
#define NG     4
#define FLAT   32768    // G * (EOUT*POUT) = 4*8192
#define GSZ    8192
#define CT     600      // tokens per chunk
#define NCH    4        // BN_TOK / CT
#define KSP    32       // split-K ways for gemm2
#define KRANGE (FLAT / KSP)   // 1024
#define LN_EPS 1e-5f

typedef __attribute__((ext_vector_type(8))) short bf16x8;
typedef __attribute__((ext_vector_type(4))) float f32x4;
typedef __hip_bfloat16 bf16;

__device__ __forceinline__ float bf2f(ushort u) {
  union { unsigned int i; float f; } c;
  c.i = ((unsigned int)u) << 16;
  return c.f;
}

// ---------------------------------------------------------------- fp32 -> bf16 cast
__global__ __launch_bounds__(256) void cast_k(const float* __restrict__ in,
                                              bf16* __restrict__ out, int n4) {
  int i = blockIdx.x * 256 + threadIdx.x;
  if (i < n4) {
    float4 v = ((const float4*)in)[i];
    bf16 tmp[4] = {__float2bfloat16(v.x), __float2bfloat16(v.y),
                   __float2bfloat16(v.z), __float2bfloat16(v.w)};
    ((ushort4*)out)[i] = *(const ushort4*)tmp;
  }
}

// ---------------------------------------------------------------- W = base_w + lora_B@lora_A (bf16, row-major [QDIM][FLAT])
__global__ __launch_bounds__(256) void build_wb_k(
    const float* __restrict__ base_w, const float* __restrict__ lora_A,
    const float* __restrict__ lora_B, bf16* __restrict__ Wb) {
  int jb = blockIdx.x * 256;
  int i0 = blockIdx.y * 16;
  int tid = threadIdx.x;
  __shared__ float lB[16][64];
  for (int e = tid; e < 16 * 64; e += 256)
    lB[e >> 6][e & 63] = lora_B[(size_t)(i0 + (e >> 6)) * 64 + (e & 63)];
  __syncthreads();
  int j = jb + tid;
  float acc[16] = {};
  for (int r = 0; r < 64; ++r) {
    float la = lora_A[(size_t)r * FLAT + j];
#pragma unroll
    for (int i = 0; i < 16; ++i) acc[i] += lB[i][r] * la;
  }
#pragma unroll
  for (int i = 0; i < 16; ++i)
    Wb[(size_t)(i0 + i) * FLAT + j] =
        __float2bfloat16(base_w[(size_t)(i0 + i) * FLAT + j] + acc[i]);
}

// ---------------------------------------------------------------- generic MFMA GEMM: C = A @ B^T + bias
// A [M][K] bf16 row-major (rows clamped to M-1 for OOB loads),
// B [N][K] bf16 row-major, C [M][ldc] (bf16 if OBF else f32), bias per col.
template <bool OBF>
__global__ __launch_bounds__(256) void gemm_nt(
    const bf16* __restrict__ A, const bf16* __restrict__ B,
    const float* __restrict__ bias, void* __restrict__ Cout,
    int M, int K, int ldc) {
  __shared__ ushort As[128 * 32];  // 8 KB
  __shared__ ushort Bs[128 * 32];  // 8 KB
  int tid = threadIdx.x;
  int w = tid >> 6, lane = tid & 63;
  int m0 = blockIdx.x * 128;
  int n0 = blockIdx.y * 128;
  int wm = (w & 1) * 64, wn = (w >> 1) * 64;
  f32x4 acc[4][4] = {};
  for (int kb = 0; kb < K; kb += 32) {
#pragma unroll
    for (int i = 0; i < 2; ++i) {
      int chunk = (w * 2 + i) * 64 + lane;  // 0..511, 16B each
      int row = chunk >> 2;
      int kc = (chunk & 3) * 8;
      int grow = m0 + row;
      if (grow >= M) grow = M - 1;  // clamp OOB token rows
      const bf16* src = A + (size_t)grow * K + kb + kc;
      __builtin_amdgcn_global_load_lds(
          (const __attribute__((address_space(1))) void*)src,
          (__attribute__((address_space(3))) void*)(As + (size_t)chunk * 8), 16, 0, 0);
    }
#pragma unroll
    for (int i = 0; i < 2; ++i) {
      int chunk = (w * 2 + i) * 64 + lane;
      int row = chunk >> 2;
      int kc = (chunk & 3) * 8;
      const bf16* src = B + (size_t)(n0 + row) * K + kb + kc;
      __builtin_amdgcn_global_load_lds(
          (const __attribute__((address_space(1))) void*)src,
          (__attribute__((address_space(3))) void*)(Bs + (size_t)chunk * 8), 16, 0, 0);
    }
    __syncthreads();
    bf16x8 af[4], bfr[4];
#pragma unroll
    for (int i = 0; i < 4; ++i) {
      int r = wm + i * 16 + (lane & 15);
      af[i] = *(const bf16x8*)&As[r * 32 + (lane >> 4) * 8];
      int c = wn + i * 16 + (lane & 15);
      bfr[i] = *(const bf16x8*)&Bs[c * 32 + (lane >> 4) * 8];
    }
#pragma unroll
    for (int i = 0; i < 4; ++i)
#pragma unroll
      for (int j = 0; j < 4; ++j)
        acc[i][j] = __builtin_amdgcn_mfma_f32_16x16x32_bf16(af[i], bfr[j], acc[i][j], 0, 0, 0);
    __syncthreads();
  }
#pragma unroll
  for (int i = 0; i < 4; ++i) {
    int rb = m0 + wm + i * 16 + (lane >> 4) * 4;
#pragma unroll
    for (int j = 0; j < 4; ++j) {
      int col = n0 + wn + j * 16 + (lane & 15);
      float b = bias[col];
#pragma unroll
      for (int r = 0; r < 4; ++r) {
        if (rb + r < M) {
          float v = acc[i][j][r] + b;
          if (OBF)
            ((bf16*)Cout)[(size_t)(rb + r) * ldc + col] = __float2bfloat16(v);
          else
            ((float*)Cout)[(size_t)(rb + r) * ldc + col] = v;
        }
      }
    }
  }
}

// ---------------------------------------------------------------- chain (fp32 VALU; reads bf16 common, writes bf16 out2 in place)
__device__ __forceinline__ void block_red2(float& s, float& sq, float* redS,
                                           float* redQ, int tid) {
#pragma unroll
  for (int off = 32; off > 0; off >>= 1) {
    s += __shfl_down(s, off);
    sq += __shfl_down(sq, off);
  }
  int w = tid >> 6;
  if ((tid & 63) == 0) { redS[w] = s; redQ[w] = sq; }
  __syncthreads();
  s = redS[0] + redS[1] + redS[2] + redS[3];
  sq = redQ[0] + redQ[1] + redQ[2] + redQ[3];
}

__global__ __launch_bounds__(256) void chain_k(
    const float* __restrict__ x, const float* __restrict__ priv,
    const float* __restrict__ ml, const float* __restrict__ mr,
    const float* __restrict__ sl, const float* __restrict__ sr,
    bf16* __restrict__ common, int t0) {
  int tid = threadIdx.x;
  int tl = blockIdx.x;
  int g = blockIdx.y;
  int t = t0 + tl;
  __shared__ float Ms[64][64];
  __shared__ float Ss[128][32];
  __shared__ float xs[32][64];
  __shared__ float o1[32][64];
  __shared__ float mzs[64], szs[64];
  __shared__ float Am[64][8];
  __shared__ float Aso[128][8];
  __shared__ float redS[4], redQ[4];

  if (tid < 64) mzs[tid] = priv[(size_t)t * 512 + g * 64 + tid];
  else if (tid < 128) szs[tid - 64] = priv[(size_t)t * 512 + 256 + g * 64 + (tid - 64)];
  __syncthreads();

  for (int e = tid; e < 512; e += 256) {
    int c = e >> 3, l = e & 7;
    float s = 0.f;
#pragma unroll
    for (int k = 0; k < 8; ++k) s += ml[g * 512 + c * 8 + k] * mzs[k * 8 + l];
    Am[c][l] = s;
  }
  for (int e = tid; e < 1024; e += 256) {
    int o = e >> 3, l = e & 7;
    float s = 0.f;
#pragma unroll
    for (int k = 0; k < 8; ++k) s += sl[g * 1024 + o * 8 + k] * szs[k * 8 + l];
    Aso[o][l] = s;
  }
  __syncthreads();

  bf16* cm = common + (size_t)tl * FLAT + g * GSZ;
  // M = Mc + Am @ mr   (16 contiguous bf16 per thread)
  {
    int e0 = tid * 16;
    int c = e0 >> 6, d0 = e0 & 63;
    bf16x8 v0 = *(const bf16x8*)&cm[e0];
    bf16x8 v1 = *(const bf16x8*)&cm[e0 + 8];
#pragma unroll
    for (int j = 0; j < 16; ++j) {
      int d = d0 + j;
      float mp = 0.f;
#pragma unroll
      for (int l = 0; l < 8; ++l) mp += Am[c][l] * mr[g * 512 + l * 64 + d];
      ushort u = (j < 8) ? (ushort)v0[j] : (ushort)v1[j - 8];
      Ms[c][d] = bf2f(u) + mp;
    }
  }
  // S = Sc + Aso @ sr
  {
    int e0 = tid * 16;
    int o = e0 >> 5, p0 = e0 & 31;
    bf16x8 v0 = *(const bf16x8*)&cm[4096 + e0];
    bf16x8 v1 = *(const bf16x8*)&cm[4096 + e0 + 8];
#pragma unroll
    for (int j = 0; j < 16; ++j) {
      int p = p0 + j;
      float sp = 0.f;
#pragma unroll
      for (int l = 0; l < 8; ++l) sp += Aso[o][l] * sr[g * 256 + l * 32 + p];
      ushort u = (j < 8) ? (ushort)v0[j] : (ushort)v1[j - 8];
      Ss[o][p] = bf2f(u) + sp;
    }
  }
  {
    const float4* xg = (const float4*)(x + (size_t)t * 8192 + g * 2048);
    float4 a = xg[tid];
    float4 b = xg[tid + 256];
    ((float4*)xs)[tid] = a;
    ((float4*)xs)[tid + 256] = b;
  }
  __syncthreads();

  int d = tid & 63, q4 = tid >> 6;
  float a1[8] = {};
  for (int c = 0; c < 64; ++c) {
    float m = Ms[c][d];
#pragma unroll
    for (int j = 0; j < 8; ++j) a1[j] += xs[q4 * 8 + j][c] * m;
  }
  float s = 0.f, sq = 0.f;
#pragma unroll
  for (int j = 0; j < 8; ++j) { s += a1[j]; sq += a1[j] * a1[j]; }
  block_red2(s, sq, redS, redQ, tid);
  float mean = s * (1.f / 2048.f);
  float var = sq * (1.f / 2048.f) - mean * mean;
  float rs = rsqrtf(var + LN_EPS);
#pragma unroll
  for (int j = 0; j < 8; ++j) {
    float v = (a1[j] - mean) * rs;
    o1[q4 * 8 + j][d] = v > 0.f ? v : 0.f;
  }
  __syncthreads();

  float a2[32] = {};
  for (int p = 0; p < 32; ++p) {
    float v = o1[p][d];
#pragma unroll
    for (int j = 0; j < 32; ++j) a2[j] += Ss[q4 * 32 + j][p] * v;
  }
  s = 0.f; sq = 0.f;
#pragma unroll
  for (int j = 0; j < 32; ++j) { s += a2[j]; sq += a2[j] * a2[j]; }
  block_red2(s, sq, redS, redQ, tid);
  float mean2 = s * (1.f / 8192.f);
  float var2 = sq * (1.f / 8192.f) - mean2 * mean2;
  float rs2 = rsqrtf(var2 + LN_EPS);
#pragma unroll
  for (int j = 0; j < 32; ++j) {
    float v = (a2[j] - mean2) * rs2;
    cm[(q4 * 32 + j) * 64 + d] = __float2bfloat16(v > 0.f ? v : 0.f);
  }
}

// ---------------------------------------------------------------- GEMM2 (MFMA split-K): partial[ks] = o2b @ Wb^T (K-slice)
__global__ __launch_bounds__(256) void gemm2_mfma(
    const bf16* __restrict__ o2b, const bf16* __restrict__ Wb,
    float* __restrict__ partial) {
  __shared__ ushort As[128 * 32];
  __shared__ ushort Bs[128 * 32];
  int tid = threadIdx.x;
  int w = tid >> 6, lane = tid & 63;
  int m0 = blockIdx.x * 128;
  int n0 = blockIdx.y * 128;
  int kz = blockIdx.z;
  int wm = (w & 1) * 64, wn = (w >> 1) * 64;
  f32x4 acc[4][4] = {};
  for (int kb = kz * KRANGE; kb < (kz + 1) * KRANGE; kb += 32) {
#pragma unroll
    for (int i = 0; i < 2; ++i) {
      int chunk = (w * 2 + i) * 64 + lane;
      int row = chunk >> 2;
      int kc = (chunk & 3) * 8;
      int grow = m0 + row;
      if (grow >= CT) grow = CT - 1;
      const bf16* src = o2b + (size_t)grow * FLAT + kb + kc;
      __builtin_amdgcn_global_load_lds(
          (const __attribute__((address_space(1))) void*)src,
          (__attribute__((address_space(3))) void*)(As + (size_t)chunk * 8), 16, 0, 0);
    }
#pragma unroll
    for (int i = 0; i < 2; ++i) {
      int chunk = (w * 2 + i) * 64 + lane;
      int row = chunk >> 2;
      int kc = (chunk & 3) * 8;
      const bf16* src = Wb + (size_t)(n0 + row) * FLAT + kb + kc;
      __builtin_amdgcn_global_load_lds(
          (const __attribute__((address_space(1))) void*)src,
          (__attribute__((address_space(3))) void*)(Bs + (size_t)chunk * 8), 16, 0, 0);
    }
    __syncthreads();
    bf16x8 af[4], bfr[4];
#pragma unroll
    for (int i = 0; i < 4; ++i) {
      int r = wm + i * 16 + (lane & 15);
      af[i] = *(const bf16x8*)&As[r * 32 + (lane >> 4) * 8];
      int c = wn + i * 16 + (lane & 15);
      bfr[i] = *(const bf16x8*)&Bs[c * 32 + (lane >> 4) * 8];
    }
#pragma unroll
    for (int i = 0; i < 4; ++i)
#pragma unroll
      for (int j = 0; j < 4; ++j)
        acc[i][j] = __builtin_amdgcn_mfma_f32_16x16x32_bf16(af[i], bfr[j], acc[i][j], 0, 0, 0);
    __syncthreads();
  }
#pragma unroll
  for (int i = 0; i < 4; ++i) {
    int rb = m0 + wm + i * 16 + (lane >> 4) * 4;
#pragma unroll
    for (int j = 0; j < 4; ++j) {
      int col = n0 + wn + j * 16 + (lane & 15);
#pragma unroll
      for (int r = 0; r < 4; ++r)
        if (rb + r < CT)
          partial[((size_t)kz * CT + rb + r) * QDIM + col] = acc[i][j][r];
    }
  }
}

// ---------------------------------------------------------------- finish: reduce split-K + bias + residual + LN
__global__ __launch_bounds__(256) void finish_k(
    const float* __restrict__ partial, const float* __restrict__ query,
    const float* __restrict__ out_bias, const float* __restrict__ gamma,
    const float* __restrict__ beta, float* __restrict__ out, int t0) {
  int tid = threadIdx.x;
  int tl = blockIdx.x;
  int t = t0 + tl;
  __shared__ float redS[4], redQ[4];
  float s = 0.f;
  for (int ks = 0; ks < KSP; ++ks)
    s += partial[((size_t)ks * CT + tl) * QDIM + tid];
  float v = s + out_bias[tid] + query[(size_t)t * QDIM + tid];
  float sum = v, sqv = v * v;
  block_red2(sum, sqv, redS, redQ, tid);
  float mean = sum * (1.f / 256.f);
  float var = sqv * (1.f / 256.f) - mean * mean;
  out[(size_t)t * QDIM + tid] =
      (v - mean) * rsqrtf(var + LN_EPS) * gamma[tid] + beta[tid];
}

// ---------------------------------------------------------------- launch
extern "C" void kernel_launch(void* const* d_in, const int* in_sizes, int n_in,
                              void* d_out, int out_size, void* d_ws, size_t ws_size,
                              hipStream_t stream) {
  const float* x       = (const float*)d_in[1];
  const float* query   = (const float*)d_in[2];
  const float* cpg_w   = (const float*)d_in[3];
  const float* cpg_b   = (const float*)d_in[4];
  const float* ppg_w   = (const float*)d_in[5];
  const float* ppg_b   = (const float*)d_in[6];
  const float* ml      = (const float*)d_in[7];
  const float* mr      = (const float*)d_in[8];
  const float* sl      = (const float*)d_in[9];
  const float* sr      = (const float*)d_in[10];
  const float* base_w  = (const float*)d_in[11];
  const float* lora_A  = (const float*)d_in[12];
  const float* lora_B  = (const float*)d_in[13];
  const float* out_bias= (const float*)d_in[14];
  const float* gamma   = (const float*)d_in[15];
  const float* beta    = (const float*)d_in[16];
  float* out = (float*)d_out;

  float* wsf = (float*)d_ws;
  // ws layout (float offsets):
  bf16*  Wb      = (bf16*)(wsf + 0);           // 256x32768 bf16 =  4,194,304 f
  bf16*  cpg_wb  = (bf16*)(wsf + 4194304);     // 32768x256 bf16 =  4,194,304 f
  bf16*  ppg_wb  = (bf16*)(wsf + 8388608);     // 512x256 bf16   =     65,536 f
  bf16*  qb      = (bf16*)(wsf + 8454144);     // 2400x256 bf16  =    307,200 f
  float* privb   = wsf + 8761344;              // 2400x512 f32   =  1,228,800 f
  bf16*  commonb = (bf16*)(wsf + 9990144);     // 600x32768 bf16 =  9,830,400 f (also out2, in place)
  float* partialb= wsf + 19820544;             // 32x600x256 f32 =  4,915,200 f
  // total = 24,735,744 floats = 98.9 MB

  // prep (once per call)
  cast_k<<<dim3(FLAT * QDIM / 4 / 256), 256, 0, stream>>>(cpg_w, cpg_wb, FLAT * QDIM / 4);
  cast_k<<<dim3(512 * QDIM / 4 / 256), 256, 0, stream>>>(ppg_w, ppg_wb, 512 * QDIM / 4);
  cast_k<<<dim3(BN_TOK * QDIM / 4 / 256), 256, 0, stream>>>(query, qb, BN_TOK * QDIM / 4);
  build_wb_k<<<dim3(FLAT / 256, QDIM / 16), 256, 0, stream>>>(base_w, lora_A, lora_B, Wb);
  // priv = qb @ ppg_wb^T + ppg_b  (M=2400, N=512, K=256, f32 out)
  gemm_nt<false><<<dim3((BN_TOK + 127) / 128, 512 / 128), 256, 0, stream>>>(
      qb, ppg_wb, ppg_b, privb, BN_TOK, QDIM, 512);

  for (int ch = 0; ch < NCH; ++ch) {
    int t0 = ch * CT;
    // common = qb[chunk] @ cpg_wb^T + cpg_b  (M=600, N=32768, bf16 out)
    gemm_nt<true><<<dim3((CT + 127) / 128, FLAT / 128), 256, 0, stream>>>(
        qb + (size_t)t0 * QDIM, cpg_wb, cpg_b, commonb, CT, QDIM, FLAT);
    chain_k<<<dim3(CT, NG), 256, 0, stream>>>(x, privb, ml, mr, sl, sr, commonb, t0);
    gemm2_mfma<<<dim3((CT + 127) / 128, QDIM / 128, KSP), 256, 0, stream>>>(commonb, Wb, partialb);
    finish_k<<<dim3(CT), 256, 0, stream>>>(partialb, query, out_bias, gamma, beta, out, t0);
  }
}

// Round 4
// 472.890 us; speedup vs baseline: 9.1747x; 1.4720x over previous
//
#include <hip/hip_runtime.h>
#include <hip/hip_bf16.h>

// Problem constants
#define BN_TOK 2400     // B*N = 8*300
#define QDIM   256
#define NG     4
#define FLAT   32768    // G * (EOUT*POUT) = 4*8192
#define GSZ    8192
#define CT     600      // tokens per chunk
#define NCH    4        // BN_TOK / CT
#define KSP    32       // split-K ways for gemm2
#define KRANGE (FLAT / KSP)   // 1024
#define LN_EPS 1e-5f
#define CPAD   78       // row stride (ushorts) for [*][64-c] tiles: 39 dwords, odd -> conflict-free
#define PPAD   42       // row stride (ushorts) for [*][32-p] tiles: 21 dwords, odd -> conflict-free

typedef __attribute__((ext_vector_type(8))) short bf16x8;
typedef __attribute__((ext_vector_type(4))) float f32x4;
typedef __hip_bfloat16 bf16;

__device__ __forceinline__ float bf2f(ushort u) {
  union { unsigned int i; float f; } c;
  c.i = ((unsigned int)u) << 16;
  return c.f;
}
__device__ __forceinline__ ushort f2u(float f) {
  bf16 h = __float2bfloat16(f);
  union { bf16 h; ushort u; } c; c.h = h; return c.u;
}

// ---------------------------------------------------------------- fp32 -> bf16 cast
__global__ __launch_bounds__(256) void cast_k(const float* __restrict__ in,
                                              bf16* __restrict__ out, int n4) {
  int i = blockIdx.x * 256 + threadIdx.x;
  if (i < n4) {
    float4 v = ((const float4*)in)[i];
    bf16 tmp[4] = {__float2bfloat16(v.x), __float2bfloat16(v.y),
                   __float2bfloat16(v.z), __float2bfloat16(v.w)};
    ((ushort4*)out)[i] = *(const ushort4*)tmp;
  }
}

// ---------------------------------------------------------------- W = base_w + lora_B@lora_A (bf16, row-major [QDIM][FLAT])
__global__ __launch_bounds__(256) void build_wb_k(
    const float* __restrict__ base_w, const float* __restrict__ lora_A,
    const float* __restrict__ lora_B, bf16* __restrict__ Wb) {
  int jb = blockIdx.x * 256;
  int i0 = blockIdx.y * 16;
  int tid = threadIdx.x;
  __shared__ float lB[16][64];
  for (int e = tid; e < 16 * 64; e += 256)
    lB[e >> 6][e & 63] = lora_B[(size_t)(i0 + (e >> 6)) * 64 + (e & 63)];
  __syncthreads();
  int j = jb + tid;
  float acc[16] = {};
  for (int r = 0; r < 64; ++r) {
    float la = lora_A[(size_t)r * FLAT + j];
#pragma unroll
    for (int i = 0; i < 16; ++i) acc[i] += lB[i][r] * la;
  }
#pragma unroll
  for (int i = 0; i < 16; ++i)
    Wb[(size_t)(i0 + i) * FLAT + j] =
        __float2bfloat16(base_w[(size_t)(i0 + i) * FLAT + j] + acc[i]);
}

// ---------------------------------------------------------------- generic MFMA GEMM: C = A @ B^T + bias
template <bool OBF>
__global__ __launch_bounds__(256) void gemm_nt(
    const bf16* __restrict__ A, const bf16* __restrict__ B,
    const float* __restrict__ bias, void* __restrict__ Cout,
    int M, int K, int ldc) {
  __shared__ ushort As[128 * 32];
  __shared__ ushort Bs[128 * 32];
  int tid = threadIdx.x;
  int w = tid >> 6, lane = tid & 63;
  int m0 = blockIdx.x * 128;
  int n0 = blockIdx.y * 128;
  int wm = (w & 1) * 64, wn = (w >> 1) * 64;
  f32x4 acc[4][4] = {};
  for (int kb = 0; kb < K; kb += 32) {
#pragma unroll
    for (int i = 0; i < 2; ++i) {
      int chunk = (w * 2 + i) * 64 + lane;
      int row = chunk >> 2;
      int kc = (chunk & 3) * 8;
      int grow = m0 + row;
      if (grow >= M) grow = M - 1;
      const bf16* src = A + (size_t)grow * K + kb + kc;
      __builtin_amdgcn_global_load_lds(
          (const __attribute__((address_space(1))) void*)src,
          (__attribute__((address_space(3))) void*)(As + (size_t)chunk * 8), 16, 0, 0);
    }
#pragma unroll
    for (int i = 0; i < 2; ++i) {
      int chunk = (w * 2 + i) * 64 + lane;
      int row = chunk >> 2;
      int kc = (chunk & 3) * 8;
      const bf16* src = B + (size_t)(n0 + row) * K + kb + kc;
      __builtin_amdgcn_global_load_lds(
          (const __attribute__((address_space(1))) void*)src,
          (__attribute__((address_space(3))) void*)(Bs + (size_t)chunk * 8), 16, 0, 0);
    }
    __syncthreads();
    bf16x8 af[4], bfr[4];
#pragma unroll
    for (int i = 0; i < 4; ++i) {
      int r = wm + i * 16 + (lane & 15);
      af[i] = *(const bf16x8*)&As[r * 32 + (lane >> 4) * 8];
      int c = wn + i * 16 + (lane & 15);
      bfr[i] = *(const bf16x8*)&Bs[c * 32 + (lane >> 4) * 8];
    }
#pragma unroll
    for (int i = 0; i < 4; ++i)
#pragma unroll
      for (int j = 0; j < 4; ++j)
        acc[i][j] = __builtin_amdgcn_mfma_f32_16x16x32_bf16(af[i], bfr[j], acc[i][j], 0, 0, 0);
    __syncthreads();
  }
#pragma unroll
  for (int i = 0; i < 4; ++i) {
    int rb = m0 + wm + i * 16 + (lane >> 4) * 4;
#pragma unroll
    for (int j = 0; j < 4; ++j) {
      int col = n0 + wn + j * 16 + (lane & 15);
      float b = bias[col];
#pragma unroll
      for (int r = 0; r < 4; ++r) {
        if (rb + r < M) {
          float v = acc[i][j][r] + b;
          if (OBF)
            ((bf16*)Cout)[(size_t)(rb + r) * ldc + col] = __float2bfloat16(v);
          else
            ((float*)Cout)[(size_t)(rb + r) * ldc + col] = v;
        }
      }
    }
  }
}

// ---------------------------------------------------------------- chain v2 (MFMA)
__device__ __forceinline__ void block_red2(float& s, float& sq, float* redS,
                                           float* redQ, int tid) {
#pragma unroll
  for (int off = 32; off > 0; off >>= 1) {
    s += __shfl_down(s, off);
    sq += __shfl_down(sq, off);
  }
  int w = tid >> 6;
  if ((tid & 63) == 0) { redS[w] = s; redQ[w] = sq; }
  __syncthreads();
  s = redS[0] + redS[1] + redS[2] + redS[3];
  sq = redQ[0] + redQ[1] + redQ[2] + redQ[3];
}

__global__ __launch_bounds__(256) void chain_k(
    const float* __restrict__ x, const float* __restrict__ priv,
    const float* __restrict__ ml, const float* __restrict__ mr,
    const float* __restrict__ sl, const float* __restrict__ sr,
    bf16* __restrict__ common, int t0) {
  int tid = threadIdx.x;
  int tl = blockIdx.x;
  int g = blockIdx.y;
  int t = t0 + tl;
  int lane = tid & 63, w = tid >> 6;

  __shared__ ushort xsb[32 * CPAD];    // x   [p][c] bf16
  __shared__ ushort MTb[64 * CPAD];    // M^T [d][c] bf16
  __shared__ ushort Ssb[128 * PPAD];   // S   [o][p] bf16
  __shared__ ushort o1Tb[64 * PPAD];   // o1^T[d][p] bf16
  __shared__ float Am[64][8];
  __shared__ float Aso[128][8];
  __shared__ float mzs[64], szs[64];
  __shared__ float srs[8][32];
  __shared__ float redS[4], redQ[4];

  // ---- stage priv slices, sr, x
  if (tid < 64) mzs[tid] = priv[(size_t)t * 512 + g * 64 + tid];
  else if (tid < 128) szs[tid - 64] = priv[(size_t)t * 512 + 256 + g * 64 + (tid - 64)];
  srs[tid >> 5][tid & 31] = sr[g * 256 + tid];
  {
    const float4* xg = (const float4*)(x + (size_t)t * 8192 + g * 2048);
    float4 a = xg[tid * 2], b = xg[tid * 2 + 1];
    int p = tid >> 3, c0 = (tid & 7) * 8;
    bf16x8 pk;
    pk[0] = (short)f2u(a.x); pk[1] = (short)f2u(a.y);
    pk[2] = (short)f2u(a.z); pk[3] = (short)f2u(a.w);
    pk[4] = (short)f2u(b.x); pk[5] = (short)f2u(b.y);
    pk[6] = (short)f2u(b.z); pk[7] = (short)f2u(b.w);
    *(bf16x8*)&xsb[p * CPAD + c0] = pk;
  }
  __syncthreads();

  // ---- Am[c][l] = sum_k ml[g,c,k]*mz[k,l] ; Aso[o][l] = sum_k sl[g,o,k]*sz[k,l]
  for (int e = tid; e < 512; e += 256) {
    int c = e >> 3, l = e & 7;
    float s = 0.f;
#pragma unroll
    for (int k = 0; k < 8; ++k) s += ml[g * 512 + c * 8 + k] * mzs[k * 8 + l];
    Am[c][l] = s;
  }
  for (int e = tid; e < 1024; e += 256) {
    int o = e >> 3, l = e & 7;
    float s = 0.f;
#pragma unroll
    for (int k = 0; k < 8; ++k) s += sl[g * 1024 + o * 8 + k] * szs[k * 8 + l];
    Aso[o][l] = s;
  }
  __syncthreads();

  bf16* cm = common + (size_t)tl * FLAT + g * GSZ;
  const ushort* cmu = (const ushort*)cm;

  // ---- M^T[d][c] = Mc[c][d] + (Am @ mr)[c][d]  (lane owns d -> coalesced cm reads, contiguous LDS writes)
  {
    int d = tid & 63, ci = tid >> 6;  // c in [ci*16, ci*16+16)
    float mrv[8];
#pragma unroll
    for (int l = 0; l < 8; ++l) mrv[l] = mr[g * 512 + l * 64 + d];
#pragma unroll
    for (int h = 0; h < 2; ++h) {
      bf16x8 pk;
#pragma unroll
      for (int j = 0; j < 8; ++j) {
        int c = ci * 16 + h * 8 + j;
        float mc = bf2f(cmu[c * 64 + d]);
        float mp = 0.f;
#pragma unroll
        for (int l = 0; l < 8; ++l) mp += Am[c][l] * mrv[l];
        pk[j] = (short)f2u(mc + mp);
      }
      *(bf16x8*)&MTb[d * CPAD + ci * 16 + h * 8] = pk;
    }
  }
  // ---- S[o][p] = Sc[o][p] + (Aso @ sr)[o][p]
  {
    int o = tid >> 1, p0 = (tid & 1) * 16;
    bf16x8 v0 = *(const bf16x8*)&cmu[4096 + o * 32 + p0];
    bf16x8 v1 = *(const bf16x8*)&cmu[4096 + o * 32 + p0 + 8];
    float asv[8];
#pragma unroll
    for (int l = 0; l < 8; ++l) asv[l] = Aso[o][l];
    bf16x8 pk0, pk1;
#pragma unroll
    for (int j = 0; j < 8; ++j) {
      float sp0 = 0.f, sp1 = 0.f;
#pragma unroll
      for (int l = 0; l < 8; ++l) {
        sp0 += asv[l] * srs[l][p0 + j];
        sp1 += asv[l] * srs[l][p0 + 8 + j];
      }
      pk0[j] = (short)f2u(bf2f((ushort)v0[j]) + sp0);
      pk1[j] = (short)f2u(bf2f((ushort)v1[j]) + sp1);
    }
    *(bf16x8*)&Ssb[o * PPAD + p0] = pk0;
    *(bf16x8*)&Ssb[o * PPAD + p0 + 8] = pk1;
  }
  __syncthreads();

  // ---- out1^T[d][p] = sum_c M^T[d][c] * x[p][c]   (wave w owns d-tile w)
  f32x4 a1[2] = {};
#pragma unroll
  for (int ks = 0; ks < 2; ++ks) {
    bf16x8 af = *(const bf16x8*)&MTb[(w * 16 + (lane & 15)) * CPAD + ks * 32 + (lane >> 4) * 8];
#pragma unroll
    for (int pt = 0; pt < 2; ++pt) {
      bf16x8 bfr = *(const bf16x8*)&xsb[(pt * 16 + (lane & 15)) * CPAD + ks * 32 + (lane >> 4) * 8];
      a1[pt] = __builtin_amdgcn_mfma_f32_16x16x32_bf16(af, bfr, a1[pt], 0, 0, 0);
    }
  }
  // ---- LN1 over 2048 + relu -> o1^T bf16
  {
    float s = 0.f, sq = 0.f;
#pragma unroll
    for (int pt = 0; pt < 2; ++pt)
#pragma unroll
      for (int r = 0; r < 4; ++r) { float v = a1[pt][r]; s += v; sq += v * v; }
    block_red2(s, sq, redS, redQ, tid);
    float mean = s * (1.f / 2048.f);
    float var = sq * (1.f / 2048.f) - mean * mean;
    float rs = rsqrtf(var + LN_EPS);
#pragma unroll
    for (int pt = 0; pt < 2; ++pt)
#pragma unroll
      for (int r = 0; r < 4; ++r) {
        float v = (a1[pt][r] - mean) * rs;
        if (v < 0.f) v = 0.f;
        int d = w * 16 + (lane >> 4) * 4 + r;
        int p = pt * 16 + (lane & 15);
        o1Tb[d * PPAD + p] = f2u(v);
      }
  }
  __syncthreads();

  // ---- out2[o][d] = sum_p S[o][p] * o1^T[d][p]   (wave w owns o-tiles 2w,2w+1)
  f32x4 a2[2][4] = {};
  {
    bf16x8 bfd[4];
#pragma unroll
    for (int dj = 0; dj < 4; ++dj)
      bfd[dj] = *(const bf16x8*)&o1Tb[(dj * 16 + (lane & 15)) * PPAD + (lane >> 4) * 8];
#pragma unroll
    for (int oi = 0; oi < 2; ++oi) {
      bf16x8 af = *(const bf16x8*)&Ssb[((2 * w + oi) * 16 + (lane & 15)) * PPAD + (lane >> 4) * 8];
#pragma unroll
      for (int dj = 0; dj < 4; ++dj)
        a2[oi][dj] = __builtin_amdgcn_mfma_f32_16x16x32_bf16(af, bfd[dj], a2[oi][dj], 0, 0, 0);
    }
  }
  // ---- LN2 over 8192 + relu -> write bf16 in place
  {
    float s = 0.f, sq = 0.f;
#pragma unroll
    for (int oi = 0; oi < 2; ++oi)
#pragma unroll
      for (int dj = 0; dj < 4; ++dj)
#pragma unroll
        for (int r = 0; r < 4; ++r) { float v = a2[oi][dj][r]; s += v; sq += v * v; }
    block_red2(s, sq, redS, redQ, tid);
    float mean = s * (1.f / 8192.f);
    float var = sq * (1.f / 8192.f) - mean * mean;
    float rs = rsqrtf(var + LN_EPS);
#pragma unroll
    for (int oi = 0; oi < 2; ++oi)
#pragma unroll
      for (int dj = 0; dj < 4; ++dj)
#pragma unroll
        for (int r = 0; r < 4; ++r) {
          float v = (a2[oi][dj][r] - mean) * rs;
          if (v < 0.f) v = 0.f;
          int o = (2 * w + oi) * 16 + (lane >> 4) * 4 + r;
          int d = dj * 16 + (lane & 15);
          cm[o * 64 + d] = __float2bfloat16(v);
        }
  }
}

// ---------------------------------------------------------------- GEMM2 (MFMA split-K)
__global__ __launch_bounds__(256) void gemm2_mfma(
    const bf16* __restrict__ o2b, const bf16* __restrict__ Wb,
    float* __restrict__ partial) {
  __shared__ ushort As[128 * 32];
  __shared__ ushort Bs[128 * 32];
  int tid = threadIdx.x;
  int w = tid >> 6, lane = tid & 63;
  int m0 = blockIdx.x * 128;
  int n0 = blockIdx.y * 128;
  int kz = blockIdx.z;
  int wm = (w & 1) * 64, wn = (w >> 1) * 64;
  f32x4 acc[4][4] = {};
  for (int kb = kz * KRANGE; kb < (kz + 1) * KRANGE; kb += 32) {
#pragma unroll
    for (int i = 0; i < 2; ++i) {
      int chunk = (w * 2 + i) * 64 + lane;
      int row = chunk >> 2;
      int kc = (chunk & 3) * 8;
      int grow = m0 + row;
      if (grow >= CT) grow = CT - 1;
      const bf16* src = o2b + (size_t)grow * FLAT + kb + kc;
      __builtin_amdgcn_global_load_lds(
          (const __attribute__((address_space(1))) void*)src,
          (__attribute__((address_space(3))) void*)(As + (size_t)chunk * 8), 16, 0, 0);
    }
#pragma unroll
    for (int i = 0; i < 2; ++i) {
      int chunk = (w * 2 + i) * 64 + lane;
      int row = chunk >> 2;
      int kc = (chunk & 3) * 8;
      const bf16* src = Wb + (size_t)(n0 + row) * FLAT + kb + kc;
      __builtin_amdgcn_global_load_lds(
          (const __attribute__((address_space(1))) void*)src,
          (__attribute__((address_space(3))) void*)(Bs + (size_t)chunk * 8), 16, 0, 0);
    }
    __syncthreads();
    bf16x8 af[4], bfr[4];
#pragma unroll
    for (int i = 0; i < 4; ++i) {
      int r = wm + i * 16 + (lane & 15);
      af[i] = *(const bf16x8*)&As[r * 32 + (lane >> 4) * 8];
      int c = wn + i * 16 + (lane & 15);
      bfr[i] = *(const bf16x8*)&Bs[c * 32 + (lane >> 4) * 8];
    }
#pragma unroll
    for (int i = 0; i < 4; ++i)
#pragma unroll
      for (int j = 0; j < 4; ++j)
        acc[i][j] = __builtin_amdgcn_mfma_f32_16x16x32_bf16(af[i], bfr[j], acc[i][j], 0, 0, 0);
    __syncthreads();
  }
#pragma unroll
  for (int i = 0; i < 4; ++i) {
    int rb = m0 + wm + i * 16 + (lane >> 4) * 4;
#pragma unroll
    for (int j = 0; j < 4; ++j) {
      int col = n0 + wn + j * 16 + (lane & 15);
#pragma unroll
      for (int r = 0; r < 4; ++r)
        if (rb + r < CT)
          partial[((size_t)kz * CT + rb + r) * QDIM + col] = acc[i][j][r];
    }
  }
}

// ---------------------------------------------------------------- finish
__global__ __launch_bounds__(256) void finish_k(
    const float* __restrict__ partial, const float* __restrict__ query,
    const float* __restrict__ out_bias, const float* __restrict__ gamma,
    const float* __restrict__ beta, float* __restrict__ out, int t0) {
  int tid = threadIdx.x;
  int tl = blockIdx.x;
  int t = t0 + tl;
  __shared__ float redS[4], redQ[4];
  float s = 0.f;
  for (int ks = 0; ks < KSP; ++ks)
    s += partial[((size_t)ks * CT + tl) * QDIM + tid];
  float v = s + out_bias[tid] + query[(size_t)t * QDIM + tid];
  float sum = v, sqv = v * v;
  block_red2(sum, sqv, redS, redQ, tid);
  float mean = sum * (1.f / 256.f);
  float var = sqv * (1.f / 256.f) - mean * mean;
  out[(size_t)t * QDIM + tid] =
      (v - mean) * rsqrtf(var + LN_EPS) * gamma[tid] + beta[tid];
}

// ---------------------------------------------------------------- launch
extern "C" void kernel_launch(void* const* d_in, const int* in_sizes, int n_in,
                              void* d_out, int out_size, void* d_ws, size_t ws_size,
                              hipStream_t stream) {
  const float* x       = (const float*)d_in[1];
  const float* query   = (const float*)d_in[2];
  const float* cpg_w   = (const float*)d_in[3];
  const float* cpg_b   = (const float*)d_in[4];
  const float* ppg_w   = (const float*)d_in[5];
  const float* ppg_b   = (const float*)d_in[6];
  const float* ml      = (const float*)d_in[7];
  const float* mr      = (const float*)d_in[8];
  const float* sl      = (const float*)d_in[9];
  const float* sr      = (const float*)d_in[10];
  const float* base_w  = (const float*)d_in[11];
  const float* lora_A  = (const float*)d_in[12];
  const float* lora_B  = (const float*)d_in[13];
  const float* out_bias= (const float*)d_in[14];
  const float* gamma   = (const float*)d_in[15];
  const float* beta    = (const float*)d_in[16];
  float* out = (float*)d_out;

  float* wsf = (float*)d_ws;
  bf16*  Wb      = (bf16*)(wsf + 0);           // 256x32768 bf16 =  4,194,304 f
  bf16*  cpg_wb  = (bf16*)(wsf + 4194304);     // 32768x256 bf16 =  4,194,304 f
  bf16*  ppg_wb  = (bf16*)(wsf + 8388608);     // 512x256 bf16   =     65,536 f
  bf16*  qb      = (bf16*)(wsf + 8454144);     // 2400x256 bf16  =    307,200 f
  float* privb   = wsf + 8761344;              // 2400x512 f32   =  1,228,800 f
  bf16*  commonb = (bf16*)(wsf + 9990144);     // 600x32768 bf16 =  9,830,400 f (also out2, in place)
  float* partialb= wsf + 19820544;             // 32x600x256 f32 =  4,915,200 f
  // total = 24,735,744 floats = 98.9 MB

  cast_k<<<dim3(FLAT * QDIM / 4 / 256), 256, 0, stream>>>(cpg_w, cpg_wb, FLAT * QDIM / 4);
  cast_k<<<dim3(512 * QDIM / 4 / 256), 256, 0, stream>>>(ppg_w, ppg_wb, 512 * QDIM / 4);
  cast_k<<<dim3(BN_TOK * QDIM / 4 / 256), 256, 0, stream>>>(query, qb, BN_TOK * QDIM / 4);
  build_wb_k<<<dim3(FLAT / 256, QDIM / 16), 256, 0, stream>>>(base_w, lora_A, lora_B, Wb);
  gemm_nt<false><<<dim3((BN_TOK + 127) / 128, 512 / 128), 256, 0, stream>>>(
      qb, ppg_wb, ppg_b, privb, BN_TOK, QDIM, 512);

  for (int ch = 0; ch < NCH; ++ch) {
    int t0 = ch * CT;
    gemm_nt<true><<<dim3((CT + 127) / 128, FLAT / 128), 256, 0, stream>>>(
        qb + (size_t)t0 * QDIM, cpg_wb, cpg_b, commonb, CT, QDIM, FLAT);
    chain_k<<<dim3(CT, NG), 256, 0, stream>>>(x, privb, ml, mr, sl, sr, commonb, t0);
    gemm2_mfma<<<dim3((CT + 127) / 128, QDIM / 128, KSP), 256, 0, stream>>>(commonb, Wb, partialb);
    finish_k<<<dim3(CT), 256, 0, stream>>>(partialb, query, out_bias, gamma, beta, out, t0);
  }
}